// Round 9
// baseline (163.329 us; speedup 1.0000x reference)
//
#include <hip/hip_runtime.h>
#include <hip/hip_bf16.h>

typedef float  f32x4  __attribute__((ext_vector_type(4)));
typedef short  bf16x8 __attribute__((ext_vector_type(8)));

#define NT      16384              // BATCH*SEQ tokens
#define NBLOCK  256                // one 512-thread block per CU -> 8 waves/CU GUARANTEED
#define WPB     8
#define NSTREAM (NBLOCK * WPB)     // 2048 streams
#define TPS     (NT / NSTREAM)     // 8 tokens per wave, strided by NSTREAM

__device__ __forceinline__ short f2bf(float x) {
  // HW conversion: compiler emits v_cvt_pk_bf16_f32 (RNE).
  return (short)__builtin_bit_cast(unsigned short, __float2bfloat16(x));
}

__global__ __launch_bounds__(512, 2)   // cap VGPR at 256 (known body uses ~176)
void kron_kernel(const float* __restrict__ x,
                 const float* __restrict__ A,
                 const float* __restrict__ Bm,
                 const float* __restrict__ bias,
                 float* __restrict__ out) {
  // Only the operand fragment tables live in LDS (32KB). X: global -> VGPR,
  // coalesced 16B/lane. 512-thread block = 2 waves/SIMD co-resident by
  // construction; k-loop unroll disabled so the body (~10KB) stays I$-resident.
  __shared__ bf16x8 AT[1024];   // [s*8+ot*2+c][lane], sigma2 baked
  __shared__ bf16x8 BT[1024];   // [s*8+pt*2+jc][lane], sigma1

  const int tid  = threadIdx.x;
  const int lane = tid & 63;
  const int w    = tid >> 6;               // 0..7
  const int g    = lane >> 4;
  const int l15  = lane & 15;
  const int sid  = blockIdx.x * WPB + w;   // stream id in [0, NSTREAM)

  // ---- one-time: operand tables, built cooperatively (2 rows/wave/table) ----
#pragma unroll
  for (int t = 0; t < 2; ++t) {                  // A: idx = s*8 + ot*2 + c
    const int idx = w * 2 + t;
    const int s = idx >> 3, ot = (idx & 7) >> 1, c = idx & 1;
    const int o = ot * 16 + l15;
    bf16x8 v;
#pragma unroll
    for (int e = 0; e < 8; ++e) {
      const int i = c * 32 + 4 * g + (e & 3) + 16 * (e >> 2);   // sigma2
      v[e] = f2bf(A[s * 4096 + o * 64 + i]);
    }
    AT[idx * 64 + lane] = v;
  }
#pragma unroll
  for (int t = 0; t < 2; ++t) {                  // B: idx = s*8 + pt*2 + jc
    const int idx = w * 2 + t;
    const int s = idx >> 3, pt = (idx & 7) >> 1, jc = idx & 1;
    const int p = pt * 16 + l15;
    bf16x8 v;
#pragma unroll
    for (int e = 0; e < 8; ++e)
      v[e] = f2bf(Bm[s * 4096 + p * 64 + (jc * 32 + 8 * g + e)]); // sigma1
    BT[idx * 64 + lane] = v;
  }

  // ---- bias -> VGPRs (16 x f32x4); acc2 is initialized from these ----
  const int pcol = 4 * g;
  f32x4 bv[4][4];
#pragma unroll
  for (int pt = 0; pt < 4; ++pt)
#pragma unroll
    for (int ot = 0; ot < 4; ++ot)
      bv[pt][ot] = *(const f32x4*)(bias + (ot * 16 + l15) * 64 + pt * 16 + pcol);

  __syncthreads();

  // X fragment loads, straight from global: lane (g,l15) reads rows 16*it+l15,
  // cols 32*jc+8g..+7 (32B = two dwordx4). A wave's 64 lanes tile full rows ->
  // coalesced. Prefetch distance = 1 body (>> HBM latency).
  f32x4 xr[4][2][2];               // in-flight fp32 X of the NEXT token (64 VGPR)
  auto loadX = [&](int kk) {
    const float* xb = x + ((size_t)(kk * NSTREAM + sid) << 12);
#pragma unroll
    for (int it = 0; it < 4; ++it)
#pragma unroll
      for (int jc = 0; jc < 2; ++jc) {
        const float* p = xb + (16 * it + l15) * 64 + 32 * jc + 8 * g;
        xr[it][jc][0] = *(const f32x4*)p;
        xr[it][jc][1] = *(const f32x4*)(p + 4);
      }
  };

  bf16x8 xf[4][2];                 // current-token bf16 fragments (32 VGPR)
  auto convX = [&]() {
#pragma unroll
    for (int it = 0; it < 4; ++it)
#pragma unroll
      for (int jc = 0; jc < 2; ++jc) {
        f32x4 f0 = xr[it][jc][0], f1 = xr[it][jc][1];
        bf16x8 t;
        t[0]=f2bf(f0[0]); t[1]=f2bf(f0[1]); t[2]=f2bf(f0[2]); t[3]=f2bf(f0[3]);
        t[4]=f2bf(f1[0]); t[5]=f2bf(f1[1]); t[6]=f2bf(f1[2]); t[7]=f2bf(f1[3]);
        xf[it][jc] = t;
      }
  };

  loadX(0);
  convX();

#pragma clang loop unroll(disable)
  for (int k = 0; k < TPS; ++k) {
    // Issue next token's 16 loads first; they drain under ~96 MFMAs + stores.
    if (k + 1 < TPS) loadX(k + 1);
    __builtin_amdgcn_sched_barrier(0);   // pin the loads ahead of the compute

    // ---- acc2 = bias (folded init) ----
    f32x4 acc2[4][4];
#pragma unroll
    for (int pt = 0; pt < 4; ++pt)
#pragma unroll
      for (int ot = 0; ot < 4; ++ot)
        acc2[pt][ot] = bv[pt][ot];

#pragma unroll
    for (int s = 0; s < 2; ++s) {
      bf16x8 bfr[4][2];
#pragma unroll
      for (int pt = 0; pt < 4; ++pt)
#pragma unroll
        for (int jc = 0; jc < 2; ++jc)
          bfr[pt][jc] = BT[(s * 8 + pt * 2 + jc) * 64 + lane];

      // Stage 1: U = X * B_s^T.  D tile (it,pt): lane holds col p=l15, rows i=4g+r.
      f32x4 a1[4][4];
#pragma unroll
      for (int a = 0; a < 4; ++a)
#pragma unroll
        for (int b = 0; b < 4; ++b)
          a1[a][b] = (f32x4){0.f, 0.f, 0.f, 0.f};
#pragma unroll
      for (int it = 0; it < 4; ++it)
#pragma unroll
        for (int pt = 0; pt < 4; ++pt)
#pragma unroll
          for (int jc = 0; jc < 2; ++jc)
            a1[it][pt] = __builtin_amdgcn_mfma_f32_16x16x32_bf16(
                xf[it][jc], bfr[pt][jc], a1[it][pt], 0, 0, 0);

      // Repack U in-lane: stage-2 A-op elem e of chunk c = a1[(e>>2)+2c][pt] reg (e&3).
      bf16x8 uf[4][2];
#pragma unroll
      for (int pt = 0; pt < 4; ++pt)
#pragma unroll
        for (int c = 0; c < 2; ++c) {
          bf16x8 t;
#pragma unroll
          for (int e = 0; e < 8; ++e)
            t[e] = f2bf(a1[(e >> 2) + 2 * c][pt][e & 3]);
          uf[pt][c] = t;
        }

      bf16x8 afr[4][2];
#pragma unroll
      for (int ot = 0; ot < 4; ++ot)
#pragma unroll
        for (int c = 0; c < 2; ++c)
          afr[ot][c] = AT[(s * 8 + ot * 2 + c) * 64 + lane];

      // Stage 2: Y^T tiles. D tile (pt,ot): lane holds col o=l15, rows p=4g+r.
#pragma unroll
      for (int pt = 0; pt < 4; ++pt)
#pragma unroll
        for (int ot = 0; ot < 4; ++ot)
#pragma unroll
          for (int c = 0; c < 2; ++c)
            acc2[pt][ot] = __builtin_amdgcn_mfma_f32_16x16x32_bf16(
                uf[pt][c], afr[ot][c], acc2[pt][ot], 0, 0, 0);
    }

    // ---- non-temporal stores (out is write-once; keep x resident in L3).
    // ot outer / pt inner: each 128B line completed by adjacent instructions.
    float* ob = out + (((size_t)(k * NSTREAM + sid)) << 12);
#pragma unroll
    for (int ot = 0; ot < 4; ++ot)
#pragma unroll
      for (int pt = 0; pt < 4; ++pt)
        __builtin_nontemporal_store(acc2[pt][ot],
            (f32x4*)(ob + (ot * 16 + l15) * 64 + pt * 16 + pcol));

    // Convert next token's X (first and only wait on the xr loads).
    if (k + 1 < TPS) convX();
  }
}

extern "C" void kernel_launch(void* const* d_in, const int* in_sizes, int n_in,
                              void* d_out, int out_size, void* d_ws, size_t ws_size,
                              hipStream_t stream) {
  const float* x    = (const float*)d_in[0];
  const float* A    = (const float*)d_in[1];
  const float* B    = (const float*)d_in[2];
  const float* bias = (const float*)d_in[3];
  float* out        = (float*)d_out;
  kron_kernel<<<dim3(NBLOCK), dim3(512), 0, stream>>>(x, A, B, bias, out);
}

// Round 10
// 161.047 us; speedup vs baseline: 1.0142x; 1.0142x over previous
//
#include <hip/hip_runtime.h>
#include <hip/hip_bf16.h>

typedef float  f32x4  __attribute__((ext_vector_type(4)));
typedef short  bf16x8 __attribute__((ext_vector_type(8)));

#define NT      16384              // BATCH*SEQ tokens
#define NBLOCK  256                // one 512-thread block per CU -> 8 waves/CU
#define WPB     8
#define NSTREAM (NBLOCK * WPB)     // 2048 streams
#define TPS     (NT / NSTREAM)     // 8 tokens per wave, strided by NSTREAM

__device__ __forceinline__ short f2bf(float x) {
  // HW conversion: compiler emits v_cvt_pk_bf16_f32 (RNE).
  return (short)__builtin_bit_cast(unsigned short, __float2bfloat16(x));
}

__global__ __launch_bounds__(512, 1)   // VGPR cap 256 (2 waves/SIMD from block
                                       // shape) -> known-good ~176-VGPR codegen,
                                       // NO spill (R9's (512,2) capped at 128
                                       // and spilled; that was the regression).
void kron_kernel(const float* __restrict__ x,
                 const float* __restrict__ A,
                 const float* __restrict__ Bm,
                 const float* __restrict__ bias,
                 float* __restrict__ out) {
  // Only the operand fragment tables live in LDS (32KB). X: global -> VGPR,
  // coalesced 16B/lane. One 512-thread block per CU = 2 waves/SIMD co-resident
  // by construction; k-loop unroll disabled so the body stays I$-resident.
  __shared__ bf16x8 AT[1024];   // [s*8+ot*2+c][lane], sigma2 baked
  __shared__ bf16x8 BT[1024];   // [s*8+pt*2+jc][lane], sigma1

  const int tid  = threadIdx.x;
  const int lane = tid & 63;
  const int w    = tid >> 6;               // 0..7
  const int g    = lane >> 4;
  const int l15  = lane & 15;
  const int sid  = blockIdx.x * WPB + w;   // stream id in [0, NSTREAM)

  // ---- one-time: operand tables, built cooperatively (2 rows/wave/table) ----
#pragma unroll
  for (int t = 0; t < 2; ++t) {                  // A: idx = s*8 + ot*2 + c
    const int idx = w * 2 + t;
    const int s = idx >> 3, ot = (idx & 7) >> 1, c = idx & 1;
    const int o = ot * 16 + l15;
    bf16x8 v;
#pragma unroll
    for (int e = 0; e < 8; ++e) {
      const int i = c * 32 + 4 * g + (e & 3) + 16 * (e >> 2);   // sigma2
      v[e] = f2bf(A[s * 4096 + o * 64 + i]);
    }
    AT[idx * 64 + lane] = v;
  }
#pragma unroll
  for (int t = 0; t < 2; ++t) {                  // B: idx = s*8 + pt*2 + jc
    const int idx = w * 2 + t;
    const int s = idx >> 3, pt = (idx & 7) >> 1, jc = idx & 1;
    const int p = pt * 16 + l15;
    bf16x8 v;
#pragma unroll
    for (int e = 0; e < 8; ++e)
      v[e] = f2bf(Bm[s * 4096 + p * 64 + (jc * 32 + 8 * g + e)]); // sigma1
    BT[idx * 64 + lane] = v;
  }

  // ---- bias -> VGPRs (16 x f32x4); acc2 is initialized from these ----
  const int pcol = 4 * g;
  f32x4 bv[4][4];
#pragma unroll
  for (int pt = 0; pt < 4; ++pt)
#pragma unroll
    for (int ot = 0; ot < 4; ++ot)
      bv[pt][ot] = *(const f32x4*)(bias + (ot * 16 + l15) * 64 + pt * 16 + pcol);

  __syncthreads();

  // X fragment loads, straight from global: lane (g,l15) reads rows 16*it+l15,
  // cols 32*jc+8g..+7 (32B = two dwordx4). A wave's 64 lanes tile full rows ->
  // coalesced. Prefetch distance = 1 body (>> HBM latency).
  f32x4 xr[4][2][2];               // in-flight fp32 X of the NEXT token (64 VGPR)
  auto loadX = [&](int kk) {
    const float* xb = x + ((size_t)(kk * NSTREAM + sid) << 12);
#pragma unroll
    for (int it = 0; it < 4; ++it)
#pragma unroll
      for (int jc = 0; jc < 2; ++jc) {
        const float* p = xb + (16 * it + l15) * 64 + 32 * jc + 8 * g;
        xr[it][jc][0] = *(const f32x4*)p;
        xr[it][jc][1] = *(const f32x4*)(p + 4);
      }
  };

  bf16x8 xf[4][2];                 // current-token bf16 fragments (32 VGPR)
  auto convX = [&]() {
#pragma unroll
    for (int it = 0; it < 4; ++it)
#pragma unroll
      for (int jc = 0; jc < 2; ++jc) {
        f32x4 f0 = xr[it][jc][0], f1 = xr[it][jc][1];
        bf16x8 t;
        t[0]=f2bf(f0[0]); t[1]=f2bf(f0[1]); t[2]=f2bf(f0[2]); t[3]=f2bf(f0[3]);
        t[4]=f2bf(f1[0]); t[5]=f2bf(f1[1]); t[6]=f2bf(f1[2]); t[7]=f2bf(f1[3]);
        xf[it][jc] = t;
      }
  };

  loadX(0);
  convX();

#pragma clang loop unroll(disable)
  for (int k = 0; k < TPS; ++k) {
    // Issue next token's 16 loads first; they drain under ~96 MFMAs + stores.
    if (k + 1 < TPS) loadX(k + 1);
    __builtin_amdgcn_sched_barrier(0);   // pin the loads ahead of the compute

    // ---- acc2 = bias (folded init) ----
    f32x4 acc2[4][4];
#pragma unroll
    for (int pt = 0; pt < 4; ++pt)
#pragma unroll
      for (int ot = 0; ot < 4; ++ot)
        acc2[pt][ot] = bv[pt][ot];

#pragma unroll
    for (int s = 0; s < 2; ++s) {
      bf16x8 bfr[4][2];
#pragma unroll
      for (int pt = 0; pt < 4; ++pt)
#pragma unroll
        for (int jc = 0; jc < 2; ++jc)
          bfr[pt][jc] = BT[(s * 8 + pt * 2 + jc) * 64 + lane];

      // Stage 1: U = X * B_s^T.  D tile (it,pt): lane holds col p=l15, rows i=4g+r.
      f32x4 a1[4][4];
#pragma unroll
      for (int a = 0; a < 4; ++a)
#pragma unroll
        for (int b = 0; b < 4; ++b)
          a1[a][b] = (f32x4){0.f, 0.f, 0.f, 0.f};
#pragma unroll
      for (int it = 0; it < 4; ++it)
#pragma unroll
        for (int pt = 0; pt < 4; ++pt)
#pragma unroll
          for (int jc = 0; jc < 2; ++jc)
            a1[it][pt] = __builtin_amdgcn_mfma_f32_16x16x32_bf16(
                xf[it][jc], bfr[pt][jc], a1[it][pt], 0, 0, 0);

      // Repack U in-lane: stage-2 A-op elem e of chunk c = a1[(e>>2)+2c][pt] reg (e&3).
      bf16x8 uf[4][2];
#pragma unroll
      for (int pt = 0; pt < 4; ++pt)
#pragma unroll
        for (int c = 0; c < 2; ++c) {
          bf16x8 t;
#pragma unroll
          for (int e = 0; e < 8; ++e)
            t[e] = f2bf(a1[(e >> 2) + 2 * c][pt][e & 3]);
          uf[pt][c] = t;
        }

      bf16x8 afr[4][2];
#pragma unroll
      for (int ot = 0; ot < 4; ++ot)
#pragma unroll
        for (int c = 0; c < 2; ++c)
          afr[ot][c] = AT[(s * 8 + ot * 2 + c) * 64 + lane];

      // Stage 2: Y^T tiles. D tile (pt,ot): lane holds col o=l15, rows p=4g+r.
#pragma unroll
      for (int pt = 0; pt < 4; ++pt)
#pragma unroll
        for (int ot = 0; ot < 4; ++ot)
#pragma unroll
          for (int c = 0; c < 2; ++c)
            acc2[pt][ot] = __builtin_amdgcn_mfma_f32_16x16x32_bf16(
                uf[pt][c], afr[ot][c], acc2[pt][ot], 0, 0, 0);
    }

    // ---- non-temporal stores (out is write-once; keep x resident in L3).
    // ot outer / pt inner: each 128B line completed by adjacent instructions.
    float* ob = out + (((size_t)(k * NSTREAM + sid)) << 12);
#pragma unroll
    for (int ot = 0; ot < 4; ++ot)
#pragma unroll
      for (int pt = 0; pt < 4; ++pt)
        __builtin_nontemporal_store(acc2[pt][ot],
            (f32x4*)(ob + (ot * 16 + l15) * 64 + pt * 16 + pcol));

    // Convert next token's X (first and only wait on the xr loads).
    if (k + 1 < TPS) convX();
  }
}

extern "C" void kernel_launch(void* const* d_in, const int* in_sizes, int n_in,
                              void* d_out, int out_size, void* d_ws, size_t ws_size,
                              hipStream_t stream) {
  const float* x    = (const float*)d_in[0];
  const float* A    = (const float*)d_in[1];
  const float* B    = (const float*)d_in[2];
  const float* bias = (const float*)d_in[3];
  float* out        = (float*)d_out;
  kron_kernel<<<dim3(NBLOCK), dim3(512), 0, stream>>>(x, A, B, bias, out);
}

// Round 11
// 113.109 us; speedup vs baseline: 1.4440x; 1.4238x over previous
//
#include <hip/hip_runtime.h>
#include <hip/hip_bf16.h>

typedef float  f32x4  __attribute__((ext_vector_type(4)));
typedef short  bf16x8 __attribute__((ext_vector_type(8)));

#define NT      16384              // BATCH*SEQ tokens
#define NBLOCK  512                // 256-thread blocks (known-good 176-VGPR codegen)
#define WPB     4
#define NSTREAM (NBLOCK * WPB)     // 2048 streams
#define TPS     (NT / NSTREAM)     // 8 tokens per wave, strided by NSTREAM

__device__ __forceinline__ short f2bf(float x) {
  // HW conversion: compiler emits v_cvt_pk_bf16_f32 (RNE).
  return (short)__builtin_bit_cast(unsigned short, __float2bfloat16(x));
}

__global__ __launch_bounds__(256, 1)   // (256,1): the only combo observed to give
                                       // spill-free ~176-VGPR codegen. 512-thr
                                       // blocks force 128 VGPR + spill (R9/R10).
void kron_kernel(const float* __restrict__ x,
                 const float* __restrict__ A,
                 const float* __restrict__ Bm,
                 const float* __restrict__ bias,
                 float* __restrict__ out) {
  // Only the operand fragment tables live in LDS (32KB). X: global -> VGPR,
  // coalesced 16B/lane. Stores are PLAIN (not non-temporal): R7/R8's nt stores
  // caused +15% HBM write amplification (307-316MB for a 268MB output) by
  // streaming partial 64B sectors; plain stores let L2 merge the two 64B
  // halves of each 128B line (R1: 273MB written, +2%).
  __shared__ bf16x8 AT[1024];   // [s*8+ot*2+c][lane], sigma2 baked
  __shared__ bf16x8 BT[1024];   // [s*8+pt*2+jc][lane], sigma1

  const int tid  = threadIdx.x;
  const int lane = tid & 63;
  const int w    = tid >> 6;
  const int g    = lane >> 4;
  const int l15  = lane & 15;
  const int sid  = blockIdx.x * WPB + w;   // stream id in [0, NSTREAM)

  // ---- one-time: operand tables, built cooperatively (4 rows/wave/table) ----
#pragma unroll
  for (int t = 0; t < 4; ++t) {                  // A: idx = s*8 + ot*2 + c
    const int idx = w * 4 + t;
    const int s = idx >> 3, ot = (idx & 7) >> 1, c = idx & 1;
    const int o = ot * 16 + l15;
    bf16x8 v;
#pragma unroll
    for (int e = 0; e < 8; ++e) {
      const int i = c * 32 + 4 * g + (e & 3) + 16 * (e >> 2);   // sigma2
      v[e] = f2bf(A[s * 4096 + o * 64 + i]);
    }
    AT[idx * 64 + lane] = v;
  }
#pragma unroll
  for (int t = 0; t < 4; ++t) {                  // B: idx = s*8 + pt*2 + jc
    const int idx = w * 4 + t;
    const int s = idx >> 3, pt = (idx & 7) >> 1, jc = idx & 1;
    const int p = pt * 16 + l15;
    bf16x8 v;
#pragma unroll
    for (int e = 0; e < 8; ++e)
      v[e] = f2bf(Bm[s * 4096 + p * 64 + (jc * 32 + 8 * g + e)]); // sigma1
    BT[idx * 64 + lane] = v;
  }

  // ---- bias -> VGPRs (16 x f32x4); acc2 is initialized from these ----
  const int pcol = 4 * g;
  f32x4 bv[4][4];
#pragma unroll
  for (int pt = 0; pt < 4; ++pt)
#pragma unroll
    for (int ot = 0; ot < 4; ++ot)
      bv[pt][ot] = *(const f32x4*)(bias + (ot * 16 + l15) * 64 + pt * 16 + pcol);

  __syncthreads();

  // X fragment loads, straight from global: lane (g,l15) reads rows 16*it+l15,
  // cols 32*jc+8g..+7 (32B = two dwordx4). A wave's 64 lanes tile full rows ->
  // coalesced. Prefetch distance = 1 body.
  f32x4 xr[4][2][2];               // in-flight fp32 X of the NEXT token (64 VGPR)
  auto loadX = [&](int kk) {
    const float* xb = x + ((size_t)(kk * NSTREAM + sid) << 12);
#pragma unroll
    for (int it = 0; it < 4; ++it)
#pragma unroll
      for (int jc = 0; jc < 2; ++jc) {
        const float* p = xb + (16 * it + l15) * 64 + 32 * jc + 8 * g;
        xr[it][jc][0] = *(const f32x4*)p;
        xr[it][jc][1] = *(const f32x4*)(p + 4);
      }
  };

  bf16x8 xf[4][2];                 // current-token bf16 fragments (32 VGPR)
  auto convX = [&]() {
#pragma unroll
    for (int it = 0; it < 4; ++it)
#pragma unroll
      for (int jc = 0; jc < 2; ++jc) {
        f32x4 f0 = xr[it][jc][0], f1 = xr[it][jc][1];
        bf16x8 t;
        t[0]=f2bf(f0[0]); t[1]=f2bf(f0[1]); t[2]=f2bf(f0[2]); t[3]=f2bf(f0[3]);
        t[4]=f2bf(f1[0]); t[5]=f2bf(f1[1]); t[6]=f2bf(f1[2]); t[7]=f2bf(f1[3]);
        xf[it][jc] = t;
      }
  };

  loadX(0);
  convX();

#pragma clang loop unroll(disable)
  for (int k = 0; k < TPS; ++k) {
    // Issue next token's 16 loads first; they drain under ~96 MFMAs + stores.
    if (k + 1 < TPS) loadX(k + 1);
    __builtin_amdgcn_sched_barrier(0);   // pin the loads ahead of the compute

    // ---- acc2 = bias (folded init) ----
    f32x4 acc2[4][4];
#pragma unroll
    for (int pt = 0; pt < 4; ++pt)
#pragma unroll
      for (int ot = 0; ot < 4; ++ot)
        acc2[pt][ot] = bv[pt][ot];

#pragma unroll
    for (int s = 0; s < 2; ++s) {
      bf16x8 bfr[4][2];
#pragma unroll
      for (int pt = 0; pt < 4; ++pt)
#pragma unroll
        for (int jc = 0; jc < 2; ++jc)
          bfr[pt][jc] = BT[(s * 8 + pt * 2 + jc) * 64 + lane];

      // Stage 1: U = X * B_s^T.  D tile (it,pt): lane holds col p=l15, rows i=4g+r.
      f32x4 a1[4][4];
#pragma unroll
      for (int a = 0; a < 4; ++a)
#pragma unroll
        for (int b = 0; b < 4; ++b)
          a1[a][b] = (f32x4){0.f, 0.f, 0.f, 0.f};
#pragma unroll
      for (int it = 0; it < 4; ++it)
#pragma unroll
        for (int pt = 0; pt < 4; ++pt)
#pragma unroll
          for (int jc = 0; jc < 2; ++jc)
            a1[it][pt] = __builtin_amdgcn_mfma_f32_16x16x32_bf16(
                xf[it][jc], bfr[pt][jc], a1[it][pt], 0, 0, 0);

      // Repack U in-lane: stage-2 A-op elem e of chunk c = a1[(e>>2)+2c][pt] reg (e&3).
      bf16x8 uf[4][2];
#pragma unroll
      for (int pt = 0; pt < 4; ++pt)
#pragma unroll
        for (int c = 0; c < 2; ++c) {
          bf16x8 t;
#pragma unroll
          for (int e = 0; e < 8; ++e)
            t[e] = f2bf(a1[(e >> 2) + 2 * c][pt][e & 3]);
          uf[pt][c] = t;
        }

      bf16x8 afr[4][2];
#pragma unroll
      for (int ot = 0; ot < 4; ++ot)
#pragma unroll
        for (int c = 0; c < 2; ++c)
          afr[ot][c] = AT[(s * 8 + ot * 2 + c) * 64 + lane];

      // Stage 2: Y^T tiles. D tile (pt,ot): lane holds col o=l15, rows p=4g+r.
#pragma unroll
      for (int pt = 0; pt < 4; ++pt)
#pragma unroll
        for (int ot = 0; ot < 4; ++ot)
#pragma unroll
          for (int c = 0; c < 2; ++c)
            acc2[pt][ot] = __builtin_amdgcn_mfma_f32_16x16x32_bf16(
                uf[pt][c], afr[ot][c], acc2[pt][ot], 0, 0, 0);
    }

    // ---- PLAIN stores (L2 merges the 64B halves into full 128B lines).
    // ot outer / pt inner: both halves of each line issued back-to-back.
    float* ob = out + (((size_t)(k * NSTREAM + sid)) << 12);
#pragma unroll
    for (int ot = 0; ot < 4; ++ot)
#pragma unroll
      for (int pt = 0; pt < 4; ++pt)
        *(f32x4*)(ob + (ot * 16 + l15) * 64 + pt * 16 + pcol) = acc2[pt][ot];

    // Convert next token's X (first and only wait on the xr loads).
    if (k + 1 < TPS) convX();
  }
}

extern "C" void kernel_launch(void* const* d_in, const int* in_sizes, int n_in,
                              void* d_out, int out_size, void* d_ws, size_t ws_size,
                              hipStream_t stream) {
  const float* x    = (const float*)d_in[0];
  const float* A    = (const float*)d_in[1];
  const float* B    = (const float*)d_in[2];
  const float* bias = (const float*)d_in[3];
  float* out        = (float*)d_out;
  kron_kernel<<<dim3(NBLOCK), dim3(256), 0, stream>>>(x, A, B, bias, out);
}

// Round 12
// 105.329 us; speedup vs baseline: 1.5507x; 1.0739x over previous
//
#include <hip/hip_runtime.h>
#include <hip/hip_bf16.h>

typedef float  f32x4  __attribute__((ext_vector_type(4)));
typedef short  bf16x8 __attribute__((ext_vector_type(8)));

#define NT      16384            // BATCH*SEQ tokens
#define NBLOCK  512              // 256-thr blocks; (256,2) + 80KB LDS -> 2 blocks/CU = 8 waves/CU
#define TPS     (NT / NBLOCK)    // 32 tokens per block (4-wave team, one token at a time)

__device__ __forceinline__ short f2bf(float x) {
  return (short)__builtin_bit_cast(unsigned short, __float2bfloat16(x));
}
__device__ __forceinline__ unsigned packbf2(float a, float b) {
  return (unsigned)(unsigned short)f2bf(a) | ((unsigned)(unsigned short)f2bf(b) << 16);
}

__device__ __forceinline__ void gload16(const float* gp, float* lp) {
  __builtin_amdgcn_global_load_lds((const __attribute__((address_space(1))) void*)gp,
                                   (__attribute__((address_space(3))) void*)lp,
                                   16, 0, 0);
}
__device__ __forceinline__ unsigned ldsaddr(const void* p) {
  return (unsigned)(uintptr_t)(const __attribute__((address_space(3))) void*)p;
}

// Team-stage one token's X (16KB): wave w stages chunks q=4w..4w+3 (4 gloads/wave).
// Same proven global-side XOR swizzle as R1/R5 (0 measured conflicts).
__device__ __forceinline__ void stageQW(float* XB, const float* gbase, int w, int lane) {
#pragma unroll
  for (int qq = 0; qq < 4; ++qq) {
    const int q = w * 4 + qq;
    const int i = q * 4 + (lane >> 4);
    const float* gp = gbase + i * 64 + (((lane & 15) ^ (i & 7)) << 2);
    gload16(gp, XB + q * 256);
  }
}

__global__ __launch_bounds__(256, 2)   // 2 waves/SIMD occupancy; 128-VGPR cap --
                                       // the cooperative split fits (~108 est).
void kron_kernel(const float* __restrict__ x,
                 const float* __restrict__ A,
                 const float* __restrict__ Bm,
                 const float* __restrict__ bias,
                 float* __restrict__ out) {
  __shared__ float  xb[2][4096];            // 32KB X double-buffer (one token/team)
  __shared__ bf16x8 AT[1024];               // 16KB [s*8+ot*2+c][lane], sigma2 baked
  __shared__ bf16x8 BT[1024];               // 16KB [s*8+pt*2+jc][lane], sigma1
  __shared__ unsigned long long Ul[2048];   // 16KB U exchange: [s][pt][g][l15][slot0..3]

  const int tid  = threadIdx.x;
  const int lane = tid & 63;
  const int w    = tid >> 6;               // wave role: stage1 it=w, stage2 pt=w
  const int g    = lane >> 4;
  const int l15  = lane & 15;
  const int blk  = blockIdx.x;

  // ---- one-time: operand tables (4 rows per wave per table) ----
#pragma unroll
  for (int t = 0; t < 4; ++t) {                  // A: idx = s*8 + ot*2 + c
    const int idx = w * 4 + t;
    const int s = idx >> 3, ot = (idx & 7) >> 1, c = idx & 1;
    const int o = ot * 16 + l15;
    bf16x8 v;
#pragma unroll
    for (int e = 0; e < 8; ++e) {
      const int i = c * 32 + 4 * g + (e & 3) + 16 * (e >> 2);   // sigma2
      v[e] = f2bf(A[s * 4096 + o * 64 + i]);
    }
    AT[idx * 64 + lane] = v;
  }
#pragma unroll
  for (int t = 0; t < 4; ++t) {                  // B: idx = s*8 + pt*2 + jc
    const int idx = w * 4 + t;
    const int s = idx >> 3, pt = (idx & 7) >> 1, jc = idx & 1;
    const int p = pt * 16 + l15;
    bf16x8 v;
#pragma unroll
    for (int e = 0; e < 8; ++e)
      v[e] = f2bf(Bm[s * 4096 + p * 64 + (jc * 32 + 8 * g + e)]); // sigma1
    BT[idx * 64 + lane] = v;
  }

  // ---- bias slice (pt=w): 4 x f32x4 = 16 VGPR ----
  f32x4 bv[4];
#pragma unroll
  for (int ot = 0; ot < 4; ++ot)
    bv[ot] = *(const f32x4*)(bias + (ot * 16 + l15) * 64 + w * 16 + 4 * g);

  __syncthreads();   // tables visible; no gloads in flight yet, drain is free

  // ---- prologue: stage tokens 0,1 ----
  stageQW(&xb[0][0], x + ((size_t)blk << 12), w, lane);
  stageQW(&xb[1][0], x + ((size_t)(blk + NBLOCK) << 12), w, lane);
  asm volatile("s_waitcnt vmcnt(4)" ::: "memory");   // own X0 chunk done
  __builtin_amdgcn_s_barrier();                      // team X0 complete

  const unsigned wsw = (unsigned)(2 * ((l15 >> 2) & 1));   // U slot swizzle bit

  for (int k = 0; k < TPS; ++k) {
    // ---- 1. xf for it=w from xb[k&1] (asm ds_read, invisible to waitcnt pass) ----
    const unsigned ba   = ldsaddr(&xb[k & 1][0]);
    const unsigned base = ba + (unsigned)(w * 16 + l15) * 256u;
    const unsigned m    = (unsigned)(l15 & 7);
    f32x4 r0[2], r1[2];
#pragma unroll
    for (int jc = 0; jc < 2; ++jc) {
      const unsigned c0 = (unsigned)(8 * jc + 2 * g);
      asm volatile("ds_read_b128 %0, %1" : "=v"(r0[jc]) : "v"(base + ((c0 ^ m) << 4)) : "memory");
      asm volatile("ds_read_b128 %0, %1" : "=v"(r1[jc]) : "v"(base + (((c0 + 1u) ^ m) << 4)) : "memory");
    }
    asm volatile("s_waitcnt lgkmcnt(0)" ::: "memory");
    __builtin_amdgcn_sched_barrier(0);

    bf16x8 xf[2];
#pragma unroll
    for (int jc = 0; jc < 2; ++jc) {
      bf16x8 t;
      t[0]=f2bf(r0[jc][0]); t[1]=f2bf(r0[jc][1]); t[2]=f2bf(r0[jc][2]); t[3]=f2bf(r0[jc][3]);
      t[4]=f2bf(r1[jc][0]); t[5]=f2bf(r1[jc][1]); t[6]=f2bf(r1[jc][2]); t[7]=f2bf(r1[jc][3]);
      xf[jc] = t;
    }

    // ---- 2. stage 1 (it=w, all pt, both s): U tiles -> LDS exchange ----
#pragma unroll
    for (int s = 0; s < 2; ++s) {
#pragma unroll
      for (int pt = 0; pt < 4; ++pt) {
        f32x4 a1 = (f32x4){0.f, 0.f, 0.f, 0.f};
#pragma unroll
        for (int jc = 0; jc < 2; ++jc)
          a1 = __builtin_amdgcn_mfma_f32_16x16x32_bf16(
              xf[jc], BT[(s * 8 + pt * 2 + jc) * 64 + lane], a1, 0, 0, 0);
        // lane holds U[w*16+4g+r][pt*16+l15], r=0..3 -> one 8B slot
        const unsigned lo = packbf2(a1[0], a1[1]);
        const unsigned hi = packbf2(a1[2], a1[3]);
        Ul[((((s * 4 + pt) * 4 + g) * 16 + l15) << 2) + ((unsigned)w ^ wsw)] =
            ((unsigned long long)hi << 32) | lo;
      }
    }

    // ---- 3. barrier 1: U visible (lgkmcnt only; vmcnt prefetch stays in flight) ----
    asm volatile("s_waitcnt lgkmcnt(0)" ::: "memory");
    __builtin_amdgcn_sched_barrier(0);
    __builtin_amdgcn_s_barrier();

    // ---- 4. stage X(k+2) into the buffer just consumed (all xf reads done) ----
    if (k + 2 < TPS)
      stageQW(&xb[k & 1][0], x + ((size_t)(blk + (k + 2) * NBLOCK) << 12), w, lane);

    // ---- 5. stage 2 (pt=w, all ot, both s) ----
    f32x4 acc[4];
#pragma unroll
    for (int ot = 0; ot < 4; ++ot) acc[ot] = bv[ot];
#pragma unroll
    for (int s = 0; s < 2; ++s) {
      bf16x8 uf[2];
#pragma unroll
      for (int c = 0; c < 2; ++c) {
        const unsigned q2 = (unsigned)((l15 >> 2) & 1);
        uf[c] = *reinterpret_cast<const bf16x8*>(
            &Ul[((((s * 4 + w) * 4 + g) * 16 + l15) << 2) + 2u * ((unsigned)c ^ q2)]);
      }
#pragma unroll
      for (int ot = 0; ot < 4; ++ot)
#pragma unroll
        for (int c = 0; c < 2; ++c)
          acc[ot] = __builtin_amdgcn_mfma_f32_16x16x32_bf16(
              uf[c], AT[(s * 8 + ot * 2 + c) * 64 + lane], acc[ot], 0, 0, 0);
    }

    // ---- 6. store (pt=w slice; bias pre-folded) ----
    float* ob = out + ((size_t)(blk + k * NBLOCK) << 12);
#pragma unroll
    for (int ot = 0; ot < 4; ++ot)
      *(f32x4*)(ob + (ot * 16 + l15) * 64 + w * 16 + 4 * g) = acc[ot];

    // ---- 7. barrier 2: counted vmcnt. Steady queue (old->new):
    // [gl(k+1) 4][st(k-1) 4][gl(k+2) 4][st(k) 4] -> vmcnt(8) retires gl(k+1)+st(k-1);
    // X(k+1) thus ready before token k+1, prefetch gl(k+2) stays in flight.
    // lgkmcnt(0): uf reads serviced before next token's U overwrite.
    asm volatile("s_waitcnt vmcnt(8) lgkmcnt(0)" ::: "memory");
    __builtin_amdgcn_sched_barrier(0);
    __builtin_amdgcn_s_barrier();
  }
}

extern "C" void kernel_launch(void* const* d_in, const int* in_sizes, int n_in,
                              void* d_out, int out_size, void* d_ws, size_t ws_size,
                              hipStream_t stream) {
  const float* x    = (const float*)d_in[0];
  const float* A    = (const float*)d_in[1];
  const float* B    = (const float*)d_in[2];
  const float* bias = (const float*)d_in[3];
  float* out        = (float*)d_out;
  kron_kernel<<<dim3(NBLOCK), dim3(256), 0, stream>>>(x, A, B, bias, out);
}